// Round 1
// baseline (1804.993 us; speedup 1.0000x reference)
//
#include <hip/hip_runtime.h>
#include <math.h>

#define D_DIM 256
#define K_CB  1024
#define EPS   1e-8f

typedef _Float16 half4_t __attribute__((ext_vector_type(4)));
typedef _Float16 half8_t __attribute__((ext_vector_type(8)));
typedef float    f32x4   __attribute__((ext_vector_type(4)));

// Split fp32 -> hi fp16 + lo fp16 (lo pre-scaled by 2^11 so it stays in fp16
// normal range; true value = hi + lo * 2^-11, residual ~2^-23 relative).
__device__ __forceinline__ void split2(const float4 v, half4_t& h, half4_t& l)
{
    h[0] = (_Float16)v.x; h[1] = (_Float16)v.y;
    h[2] = (_Float16)v.z; h[3] = (_Float16)v.w;
    l[0] = (_Float16)((v.x - (float)h[0]) * 2048.0f);
    l[1] = (_Float16)((v.y - (float)h[1]) * 2048.0f);
    l[2] = (_Float16)((v.z - (float)h[2]) * 2048.0f);
    l[3] = (_Float16)((v.w - (float)h[3]) * 2048.0f);
}

// ws layout: scales[0..K_CB) = 1/max(||codebook_k||, eps)
//            scales[K_CB..K_CB+N) = 1/(max(||latent_n||, eps) * temperature)
__global__ __launch_bounds__(256) void qnorms_kernel(
    const float* __restrict__ latent,
    const float* __restrict__ codebook,
    const float* __restrict__ temp,
    float* __restrict__ scales,
    int N)
{
    const int w = blockIdx.x * 4 + (threadIdx.x >> 6);   // one wave per row
    const int lane = threadIdx.x & 63;
    if (w >= N + K_CB) return;
    const float* src = (w < K_CB) ? (codebook + (size_t)w * D_DIM)
                                  : (latent + (size_t)(w - K_CB) * D_DIM);
    float4 v = reinterpret_cast<const float4*>(src)[lane];   // 64 lanes x 4 = 256
    float ss = v.x * v.x + v.y * v.y + v.z * v.z + v.w * v.w;
#pragma unroll
    for (int off = 32; off > 0; off >>= 1) ss += __shfl_down(ss, off, 64);
    if (lane == 0) {
        const float inv = 1.0f / fmaxf(sqrtf(ss), EPS);
        scales[w] = (w < K_CB) ? inv : inv / temp[0];
    }
}

// MFMA main kernel.
// Block: 256 threads = 4 waves (2x2 wave grid), 64 latent rows per block.
// Wave (wr,wc): rows wr*32 + rt*16, cols wc*128 + t*16 within a 256-col tile.
// fp32 GEMM emulated by fp16 split: acc_hi += a0*b0 ; acc_mid += a1*b0 + a0*b1
// (a1,b1 scaled by 2^11); dot = acc_hi + acc_mid * 2^-11.
// A-tile split into LDS once (XOR-swizzled, conflict-free frag reads).
// B streamed per [256 col x 32 d] stage, double-buffered, 1 barrier/stage.
// Fused gumbel + argmax epilogue per 256-col tile; cross-wave merge in LDS.
__global__ __launch_bounds__(256, 1) void qmain_kernel(
    const float* __restrict__ latent,
    const float* __restrict__ noise,
    const float* __restrict__ codebook,
    const float* __restrict__ scales,
    float* __restrict__ out,
    int N)
{
    __shared__ __align__(16) _Float16 A0s[64 * 256];       // 32 KB
    __shared__ __align__(16) _Float16 A1s[64 * 256];       // 32 KB
    __shared__ __align__(16) _Float16 Bs[2][2][256 * 32];  // 64 KB (dbuf x {b0,b1})
    __shared__ __align__(16) float cscale_s[K_CB];         // 4 KB
    __shared__ float vmax_s[2][64];
    __shared__ int   vidx_s[2][64];
    __shared__ int   idx_s[64];

    const int tid  = threadIdx.x;
    const int row0 = blockIdx.x * 64;
    const int wid  = tid >> 6;
    const int lane = tid & 63;
    const int wr   = wid >> 1;     // wave row-group: rows wr*32..wr*32+31
    const int wc   = wid & 1;      // wave col-half: cols wc*128..wc*128+127
    const int c16  = lane & 15;
    const int g    = lane >> 4;    // k-group for frags; row-group for C

    // ---- Stage A (64 x 256 fp32) -> split fp16 LDS, swizzled ----
    {
        const int f4   = tid & 63;         // d0 = f4*4
        const int rsub = tid >> 6;
        const int d0   = f4 * 4;
#pragma unroll
        for (int p = 0; p < 16; ++p) {
            const int row = p * 4 + rsub;
            const float4 v = reinterpret_cast<const float4*>(
                latent + (size_t)(row0 + row) * D_DIM)[f4];
            half4_t h0, h1; split2(v, h0, h1);
            const int idx = row * 256 + (d0 ^ ((row & 7) << 3));
            *reinterpret_cast<half4_t*>(&A0s[idx]) = h0;
            *reinterpret_cast<half4_t*>(&A1s[idx]) = h1;
        }
    }
    // ---- codebook scales -> LDS ----
    {
        const float4 v = reinterpret_cast<const float4*>(scales)[tid];  // 1024 floats
        reinterpret_cast<float4*>(cscale_s)[tid] = v;
    }

    // ---- B staging geometry: thread -> (col = p*32 + tid>>3, d0 = (tid&7)*4) ----
    const int colb = tid >> 3;   // 0..31
    const int dg   = tid & 7;

    // prologue: stage s=0 (ct=0, ds=0) into buf 0
#pragma unroll
    for (int p = 0; p < 8; ++p) {
        const int col = p * 32 + colb;
        const float4 v = *reinterpret_cast<const float4*>(
            codebook + (size_t)col * D_DIM + dg * 4);
        half4_t h0, h1; split2(v, h0, h1);
        const int idx = col * 32 + ((dg * 4) ^ (((col >> 1) & 3) << 3));
        *reinterpret_cast<half4_t*>(&Bs[0][0][idx]) = h0;
        *reinterpret_cast<half4_t*>(&Bs[0][1][idx]) = h1;
    }
    __syncthreads();

    // per-lane row scales (includes 1/temperature)
    float rscale[2][4];
#pragma unroll
    for (int rt = 0; rt < 2; ++rt)
#pragma unroll
        for (int j = 0; j < 4; ++j)
            rscale[rt][j] = scales[K_CB + row0 + wr * 32 + rt * 16 + g * 4 + j];

    float rmax[2][4];
    int   ridx[2][4];
#pragma unroll
    for (int rt = 0; rt < 2; ++rt)
#pragma unroll
        for (int j = 0; j < 4; ++j) { rmax[rt][j] = -INFINITY; ridx[rt][j] = 0x7fffffff; }

    f32x4 acc_hi[2][8], acc_mid[2][8];

    for (int ct = 0; ct < 4; ++ct) {
#pragma unroll
        for (int rt = 0; rt < 2; ++rt)
#pragma unroll
            for (int t = 0; t < 8; ++t)
#pragma unroll
                for (int q = 0; q < 4; ++q) { acc_hi[rt][t][q] = 0.0f; acc_mid[rt][t][q] = 0.0f; }

        for (int ds = 0; ds < 8; ++ds) {
            const int s   = ct * 8 + ds;
            const int buf = s & 1;
            const bool pf = (s < 31);
            float4 pv[8];
            if (pf) {               // prefetch next stage's fp32 codebook slice
                const int sn  = s + 1;
                const int cb2 = (sn >> 3) * 256;
                const int db2 = (sn & 7) * 32;
#pragma unroll
                for (int p = 0; p < 8; ++p) {
                    const int col = p * 32 + colb;
                    pv[p] = *reinterpret_cast<const float4*>(
                        codebook + (size_t)(cb2 + col) * D_DIM + db2 + dg * 4);
                }
            }

            // ---- MFMA block: 48 mfma_f32_16x16x32_f16 per wave per stage ----
            const int dA = ds * 32 + g * 8;
            half8_t a0[2], a1[2];
#pragma unroll
            for (int rt = 0; rt < 2; ++rt) {
                const int arow = wr * 32 + rt * 16 + c16;
                const int aidx = arow * 256 + (dA ^ ((arow & 7) << 3));
                a0[rt] = *reinterpret_cast<const half8_t*>(&A0s[aidx]);
                a1[rt] = *reinterpret_cast<const half8_t*>(&A1s[aidx]);
            }
#pragma unroll
            for (int t = 0; t < 8; ++t) {
                const int col  = wc * 128 + t * 16 + c16;
                const int bidx = col * 32 + ((g * 8) ^ (((col >> 1) & 3) << 3));
                const half8_t b0 = *reinterpret_cast<const half8_t*>(&Bs[buf][0][bidx]);
                const half8_t b1 = *reinterpret_cast<const half8_t*>(&Bs[buf][1][bidx]);
#pragma unroll
                for (int rt = 0; rt < 2; ++rt) {
                    acc_hi[rt][t]  = __builtin_amdgcn_mfma_f32_16x16x32_f16(
                        a0[rt], b0, acc_hi[rt][t], 0, 0, 0);
                    acc_mid[rt][t] = __builtin_amdgcn_mfma_f32_16x16x32_f16(
                        a1[rt], b0, acc_mid[rt][t], 0, 0, 0);
                    acc_mid[rt][t] = __builtin_amdgcn_mfma_f32_16x16x32_f16(
                        a0[rt], b1, acc_mid[rt][t], 0, 0, 0);
                }
            }

            if (pf) {               // convert + write next stage into other buffer
#pragma unroll
                for (int p = 0; p < 8; ++p) {
                    const int col = p * 32 + colb;
                    half4_t h0, h1; split2(pv[p], h0, h1);
                    const int idx = col * 32 + ((dg * 4) ^ (((col >> 1) & 3) << 3));
                    *reinterpret_cast<half4_t*>(&Bs[buf ^ 1][0][idx]) = h0;
                    *reinterpret_cast<half4_t*>(&Bs[buf ^ 1][1][idx]) = h1;
                }
            }
            __syncthreads();
        }

        // ---- epilogue for this 256-col tile: gumbel + running argmax ----
#pragma unroll
        for (int rt = 0; rt < 2; ++rt) {
#pragma unroll
            for (int j = 0; j < 4; ++j) {
                const int rowg = row0 + wr * 32 + rt * 16 + g * 4 + j;
                const float rs = rscale[rt][j];
                const float* nrow = noise + (size_t)rowg * K_CB;
                float v  = rmax[rt][j];
                int   vi = ridx[rt][j];
#pragma unroll
                for (int t = 0; t < 8; ++t) {
                    const int colg = ct * 256 + wc * 128 + t * 16 + c16;
                    const float u   = nrow[colg];
                    const float gum = -logf(-logf(u));
                    const float dot = acc_hi[rt][t][j] + acc_mid[rt][t][j] * (1.0f / 2048.0f);
                    const float l   = fmaf(dot * rs, cscale_s[colg], gum);
                    if (l > v || (l == v && colg < vi)) { v = l; vi = colg; }
                }
                rmax[rt][j] = v;
                ridx[rt][j] = vi;
            }
        }
    }

    // ---- cross-lane reduce (16 cols per group) then cross-wave merge ----
#pragma unroll
    for (int rt = 0; rt < 2; ++rt)
#pragma unroll
        for (int j = 0; j < 4; ++j) {
            float v  = rmax[rt][j];
            int   vi = ridx[rt][j];
#pragma unroll
            for (int off = 1; off < 16; off <<= 1) {
                const float ov = __shfl_xor(v, off, 64);
                const int   oi = __shfl_xor(vi, off, 64);
                if (ov > v || (ov == v && oi < vi)) { v = ov; vi = oi; }
            }
            if (c16 == 0) {
                const int rloc = wr * 32 + rt * 16 + g * 4 + j;
                vmax_s[wc][rloc] = v;
                vidx_s[wc][rloc] = vi;
            }
        }
    __syncthreads();
    if (tid < 64) {
        float v0 = vmax_s[0][tid]; int i0 = vidx_s[0][tid];
        const float v1 = vmax_s[1][tid]; const int i1 = vidx_s[1][tid];
        if (v1 > v0 || (v1 == v0 && i1 < i0)) { i0 = i1; }
        idx_s[tid] = i0;
    }
    __syncthreads();

    // ---- gather: out[row] = codebook[idx[row]] (coalesced 1KB per row) ----
    {
        const int l2 = tid & 63;
        const int rr = tid >> 6;
#pragma unroll
        for (int p = 0; p < 16; ++p) {
            const int row = rr * 16 + p;
            const int idx = idx_s[row];
            const float4 v =
                reinterpret_cast<const float4*>(codebook + (size_t)idx * D_DIM)[l2];
            reinterpret_cast<float4*>(out + (size_t)(row0 + row) * D_DIM)[l2] = v;
        }
    }
}

extern "C" void kernel_launch(void* const* d_in, const int* in_sizes, int n_in,
                              void* d_out, int out_size, void* d_ws, size_t ws_size,
                              hipStream_t stream)
{
    const float* latent   = (const float*)d_in[0];
    const float* noise    = (const float*)d_in[1];
    const float* codebook = (const float*)d_in[2];
    const float* temp     = (const float*)d_in[3];
    float* out    = (float*)d_out;
    float* scales = (float*)d_ws;                // (K_CB + N) floats
    const int N = in_sizes[0] / D_DIM;           // 131072

    const int nw = (N + K_CB + 3) / 4;           // 4 waves per block
    qnorms_kernel<<<nw, 256, 0, stream>>>(latent, codebook, temp, scales, N);
    qmain_kernel<<<N / 64, 256, 0, stream>>>(latent, noise, codebook, scales, out, N);
}